// Round 7
// baseline (630.637 us; speedup 1.0000x reference)
//
#include <hip/hip_runtime.h>
#include <hip/hip_bf16.h>
#include <math.h>

// Problem constants
#define R_   8192    // B*S rows
#define DM   1024    // d_model
#define DFF  4096    // d_ff
#define NP   64      // n_patterns
#define KN   8       // K neurons

typedef __bf16 bf16x8 __attribute__((ext_vector_type(8)));
typedef float  f32x4  __attribute__((ext_vector_type(4)));

__device__ __forceinline__ unsigned short f2bf(float f) {
  union { float f; unsigned u; } v; v.f = f;
  unsigned u = v.u;
  return (unsigned short)((u + 0x7FFFu + ((u >> 16) & 1u)) >> 16);
}

__device__ __forceinline__ float dot4(const float4 a, const float4 b) {
  return a.x * b.x + a.y * b.y + a.z * b.z + a.w * b.w;
}

__device__ __forceinline__ void fma4(float4& a, float w, const float4 s) {
  a.x += w * s.x; a.y += w * s.y; a.z += w * s.z; a.w += w * s.w;
}

// ---------------------------------------------------------------- f32 -> bf16
__global__ __launch_bounds__(256) void cvt_bf16_kernel(
    const float* __restrict__ in, unsigned short* __restrict__ out, int n8) {
  int i = blockIdx.x * 256 + threadIdx.x;
  if (i >= n8) return;
  const float4* p = (const float4*)in + (size_t)i * 2;
  float4 a = p[0], b = p[1];
  uint4 r;
  r.x = (unsigned)f2bf(a.x) | ((unsigned)f2bf(a.y) << 16);
  r.y = (unsigned)f2bf(a.z) | ((unsigned)f2bf(a.w) << 16);
  r.z = (unsigned)f2bf(b.x) | ((unsigned)f2bf(b.y) << 16);
  r.w = (unsigned)f2bf(b.z) | ((unsigned)f2bf(b.w) << 16);
  ((uint4*)out)[i] = r;
}

// -------------------------------------------------------------- v materialize
__global__ __launch_bounds__(256) void vcomp_kernel(
    const float* __restrict__ sn,    // [R_][8][1024]
    const float* __restrict__ tw,    // [R_][8]
    float* __restrict__ v)           // [R_][1024]
{
  const int r = blockIdx.x;
  const int t = threadIdx.x;
  float w[KN];
#pragma unroll
  for (int k = 0; k < KN; ++k) w[k] = tw[(size_t)r * KN + k];
  const float* base = sn + (size_t)r * (KN * DM) + t * 4;
  float4 a = {0.f, 0.f, 0.f, 0.f};
#pragma unroll
  for (int k = 0; k < KN; ++k) fma4(a, w[k], *(const float4*)(base + k * DM));
  *(float4*)(v + (size_t)r * DM + t * 4) = a;
}

// ------------------------------------------------- pattern scores/topk/softmax
__global__ __launch_bounds__(256, 2) void score_kernel(
    const float* __restrict__ v,     // [R_][1024]
    const float* __restrict__ pq,    // [64][1024]
    int*   __restrict__ out_idx,     // [R_][4]
    float* __restrict__ out_w)       // [R_][4]
{
  const int lane = threadIdx.x & 63;
  const int wave = threadIdx.x >> 6;
  const int pos0 = (blockIdx.x * 4 + wave) * 4;

  float4 vr[4][4];
#pragma unroll
  for (int p = 0; p < 4; ++p) {
    const float4* s = (const float4*)(v + (size_t)(pos0 + p) * DM + lane * 16);
    vr[p][0] = s[0]; vr[p][1] = s[1]; vr[p][2] = s[2]; vr[p][3] = s[3];
  }

  float sreg[4];
#pragma unroll 1
  for (int pat = 0; pat < NP; ++pat) {
    const float4* q = (const float4*)(pq + pat * DM + lane * 16);
    const float4 q0 = q[0], q1 = q[1], q2 = q[2], q3 = q[3];
    float part[4];
#pragma unroll
    for (int p = 0; p < 4; ++p)
      part[p] = dot4(q0, vr[p][0]) + dot4(q1, vr[p][1]) +
                dot4(q2, vr[p][2]) + dot4(q3, vr[p][3]);
#pragma unroll
    for (int off = 32; off >= 1; off >>= 1) {
#pragma unroll
      for (int p = 0; p < 4; ++p)
        part[p] += __shfl_xor(part[p], off, 64);
    }
    if (lane == pat) {
#pragma unroll
      for (int p = 0; p < 4; ++p) sreg[p] = part[p] * 0.03125f; // /sqrt(1024)
    }
  }

#pragma unroll
  for (int p = 0; p < 4; ++p) {
    float cur = sreg[p];
    float m0, m1, m2, m3; int i0, i1, i2, i3;
#define ARGMAX_STEP(MV, MI)                                   \
    {                                                         \
      float bv = cur; int bi = lane;                          \
      _Pragma("unroll")                                       \
      for (int off = 32; off >= 1; off >>= 1) {               \
        float ov = __shfl_xor(bv, off, 64);                   \
        int   oi = __shfl_xor(bi, off, 64);                   \
        if (ov > bv || (ov == bv && oi < bi)) { bv = ov; bi = oi; } \
      }                                                       \
      MV = bv; MI = bi;                                       \
      if (lane == bi) cur = -3.0e38f;                         \
    }
    ARGMAX_STEP(m0, i0) ARGMAX_STEP(m1, i1) ARGMAX_STEP(m2, i2) ARGMAX_STEP(m3, i3)
#undef ARGMAX_STEP
    const float e1 = __expf(m1 - m0), e2 = __expf(m2 - m0), e3 = __expf(m3 - m0);
    const float inv = 1.f / (1.f + e1 + e2 + e3);
    if (lane < 4) {
      const int r = pos0 + p;
      const int myi = (lane == 0) ? i0 : (lane == 1) ? i1 : (lane == 2) ? i2 : i3;
      const float mye = (lane == 0) ? 1.f : (lane == 1) ? e1 : (lane == 2) ? e2 : e3;
      out_idx[r * 4 + lane] = myi;
      out_w[r * 4 + lane] = mye * inv;
    }
  }
}

// ------------------------------------------------------- LDS-free direct GEMM
// NT layout + 16x16x32 frag pattern is line-coalesced straight from global:
// lane reads 16B at (row0 + (lane&15))*K + (lane>>4)*8; quarter-wave lanes
// {r, r+16, r+32, r+48} consume one full 64B line.  No LDS, no barriers:
// frags stream global->VGPR double-buffered; L1/L2 absorb wave multiplicity.

#define MMLOOP(MF, ACCOFF, FA, FB)                                          \
  __builtin_amdgcn_s_setprio(1);                                            \
  _Pragma("unroll") for (int m_ = 0; m_ < MF; ++m_)                         \
  _Pragma("unroll") for (int n_ = 0; n_ < 4; ++n_)                          \
    acc[(ACCOFF) + m_][n_] = __builtin_amdgcn_mfma_f32_16x16x32_bf16(       \
        FA[m_], FB[n_], acc[(ACCOFF) + m_][n_], 0, 0, 0);                   \
  __builtin_amdgcn_s_setprio(0);

// ---- GEMM1: H = gelu_gate(xb[8192][1024] @ uwb[4096][1024]^T)
// block 256x256, 8 waves (2x4), wave-tile 128x64, K=1024, NT=32, grid 512.
__global__ __launch_bounds__(512, 2) void gemm1_kernel(
    const unsigned short* __restrict__ A,
    const unsigned short* __restrict__ Bm,
    const float* __restrict__ bias,
    const int*   __restrict__ pidx,
    const float* __restrict__ pwt,
    const float* __restrict__ gates,
    unsigned short* __restrict__ H)
{
  constexpr int K_ = 1024, NT = 32;
  const int lane = threadIdx.x & 63, wid = threadIdx.x >> 6;
  const int wr = wid >> 2, wc = wid & 3;
  const int cpx = gridDim.x >> 3;
  const int swzb = ((int)blockIdx.x & 7) * cpx + ((int)blockIdx.x >> 3);
  const int brow = swzb >> 4, bcol = swzb & 15;   // 32 x 16 grid

  const unsigned short* Ap =
      A + (size_t)(brow * 256 + wr * 128 + (lane & 15)) * K_ + (lane >> 4) * 8;
  const unsigned short* Bp =
      Bm + (size_t)(bcol * 256 + wc * 64 + (lane & 15)) * K_ + (lane >> 4) * 8;

  f32x4 acc[8][4];
#pragma unroll
  for (int m = 0; m < 8; ++m)
#pragma unroll
    for (int n = 0; n < 4; ++n) acc[m][n] = (f32x4){0.f, 0.f, 0.f, 0.f};

  bf16x8 fa0[8], fb0[4], fa1[8], fb1[4];

#define LD1(FA, FB, KT)                                                     \
  { _Pragma("unroll") for (int m_ = 0; m_ < 8; ++m_)                        \
      FA[m_] = *(const bf16x8*)(Ap + m_ * 16 * K_ + (KT) * 32);             \
    _Pragma("unroll") for (int n_ = 0; n_ < 4; ++n_)                        \
      FB[n_] = *(const bf16x8*)(Bp + n_ * 16 * K_ + (KT) * 32); }

  LD1(fa0, fb0, 0)
#pragma unroll 1
  for (int kt = 0; kt < NT - 2; kt += 2) {
    LD1(fa1, fb1, kt + 1)
    MMLOOP(8, 0, fa0, fb0)
    LD1(fa0, fb0, kt + 2)
    MMLOOP(8, 0, fa1, fb1)
  }
  LD1(fa1, fb1, NT - 1)
  MMLOOP(8, 0, fa0, fb0)
  MMLOOP(8, 0, fa1, fb1)
#undef LD1

  // epilogue: C/D layout col = lane&15, row = (lane>>4)*4 + j
  const int crow0 = brow * 256 + wr * 128;
  const int ccol0 = bcol * 256 + wc * 64 + (lane & 15);
  const int rsub  = (lane >> 4) * 4;
#pragma unroll
  for (int m = 0; m < 8; ++m) {
    const int rbase = crow0 + m * 16 + rsub;
    int   ia[4][4];
    float wa[4][4];
#pragma unroll
    for (int j = 0; j < 4; ++j) {
      const int4   iq = *(const int4*)(pidx + (size_t)(rbase + j) * 4);
      const float4 wq = *(const float4*)(pwt + (size_t)(rbase + j) * 4);
      ia[j][0] = iq.x; ia[j][1] = iq.y; ia[j][2] = iq.z; ia[j][3] = iq.w;
      wa[j][0] = wq.x; wa[j][1] = wq.y; wa[j][2] = wq.z; wa[j][3] = wq.w;
    }
#pragma unroll
    for (int n = 0; n < 4; ++n) {
      const int col = ccol0 + n * 16;
      const float ub = bias[col];
#pragma unroll
      for (int j = 0; j < 4; ++j) {
        float g = wa[j][0] * gates[(size_t)ia[j][0] * DFF + col]
                + wa[j][1] * gates[(size_t)ia[j][1] * DFF + col]
                + wa[j][2] * gates[(size_t)ia[j][2] * DFF + col]
                + wa[j][3] * gates[(size_t)ia[j][3] * DFF + col];
        const float u   = acc[m][n][j] + ub;
        const float val = u * (1.f / (1.f + __expf(-g)));
        const float h   = 0.5f * val * (1.f + erff(val * 0.70710678118654752f));
        H[(size_t)(rbase + j) * DFF + col] = f2bf(h);
      }
    }
  }
}

// ---- GEMM2: out = H[8192][4096] @ dwb[1024][4096]^T + dnb
// block 256x128, 8 waves (4x2), wave-tile 64x64, K=4096, NT=128, grid 256.
__global__ __launch_bounds__(512, 2) void gemm2_kernel(
    const unsigned short* __restrict__ A,
    const unsigned short* __restrict__ Bm,
    const float* __restrict__ bias,
    float* __restrict__ O)
{
  constexpr int K_ = 4096, NT = 128;
  const int lane = threadIdx.x & 63, wid = threadIdx.x >> 6;
  const int wr = wid >> 1, wc = wid & 1;
  const int cpx = gridDim.x >> 3;
  const int swzb = ((int)blockIdx.x & 7) * cpx + ((int)blockIdx.x >> 3);
  const int brow = swzb >> 3, bcol = swzb & 7;    // 32 x 8 grid

  const unsigned short* Ap =
      A + (size_t)(brow * 256 + wr * 64 + (lane & 15)) * K_ + (lane >> 4) * 8;
  const unsigned short* Bp =
      Bm + (size_t)(bcol * 128 + wc * 64 + (lane & 15)) * K_ + (lane >> 4) * 8;

  f32x4 acc[4][4];
#pragma unroll
  for (int m = 0; m < 4; ++m)
#pragma unroll
    for (int n = 0; n < 4; ++n) acc[m][n] = (f32x4){0.f, 0.f, 0.f, 0.f};

  bf16x8 fa0[4], fb0[4], fa1[4], fb1[4];

#define LD2(FA, FB, KT)                                                     \
  { _Pragma("unroll") for (int m_ = 0; m_ < 4; ++m_)                        \
      FA[m_] = *(const bf16x8*)(Ap + m_ * 16 * K_ + (KT) * 32);             \
    _Pragma("unroll") for (int n_ = 0; n_ < 4; ++n_)                        \
      FB[n_] = *(const bf16x8*)(Bp + n_ * 16 * K_ + (KT) * 32); }

  LD2(fa0, fb0, 0)
#pragma unroll 1
  for (int kt = 0; kt < NT - 2; kt += 2) {
    LD2(fa1, fb1, kt + 1)
    MMLOOP(4, 0, fa0, fb0)
    LD2(fa0, fb0, kt + 2)
    MMLOOP(4, 0, fa1, fb1)
  }
  LD2(fa1, fb1, NT - 1)
  MMLOOP(4, 0, fa0, fb0)
  MMLOOP(4, 0, fa1, fb1)
#undef LD2

  const int crow0 = brow * 256 + wr * 64;
  const int ccol0 = bcol * 128 + wc * 64 + (lane & 15);
  const int rsub  = (lane >> 4) * 4;
#pragma unroll
  for (int m = 0; m < 4; ++m) {
    const int rbase = crow0 + m * 16 + rsub;
#pragma unroll
    for (int n = 0; n < 4; ++n) {
      const int col = ccol0 + n * 16;
      const float db = bias[col];
#pragma unroll
      for (int j = 0; j < 4; ++j)
        O[(size_t)(rbase + j) * DM + col] = acc[m][n][j] + db;
    }
  }
}

// ---------------------------------------------------------------------- launch
extern "C" void kernel_launch(void* const* d_in, const int* in_sizes, int n_in,
                              void* d_out, int out_size, void* d_ws, size_t ws_size,
                              hipStream_t stream) {
  const float* x     = (const float*)d_in[0];
  const float* tw    = (const float*)d_in[3];
  const float* sn    = (const float*)d_in[4];
  const float* pq    = (const float*)d_in[5];
  const float* gates = (const float*)d_in[6];
  const float* upw   = (const float*)d_in[7];
  const float* upb   = (const float*)d_in[8];
  const float* dnw   = (const float*)d_in[9];
  const float* dnb   = (const float*)d_in[10];
  float* out = (float*)d_out;

  char* p = (char*)d_ws;
  unsigned short* xb  = (unsigned short*)p; p += (size_t)R_ * DM * 2;
  unsigned short* uwb = (unsigned short*)p; p += (size_t)DFF * DM * 2;
  unsigned short* dwb = (unsigned short*)p; p += (size_t)DM * DFF * 2;
  unsigned short* H   = (unsigned short*)p; p += (size_t)R_ * DFF * 2;
  int*   pidx = (int*)p;   p += (size_t)R_ * 4 * sizeof(int);
  float* pwt  = (float*)p; p += (size_t)R_ * 4 * sizeof(float);
  float* vbuf = (float*)p; p += (size_t)R_ * DM * sizeof(float);

  cvt_bf16_kernel<<<(R_ * DM / 8) / 256, 256, 0, stream>>>(x, xb, R_ * DM / 8);
  cvt_bf16_kernel<<<(DFF * DM / 8) / 256, 256, 0, stream>>>(upw, uwb, DFF * DM / 8);
  cvt_bf16_kernel<<<(DM * DFF / 8) / 256, 256, 0, stream>>>(dnw, dwb, DM * DFF / 8);

  vcomp_kernel<<<R_, 256, 0, stream>>>(sn, tw, vbuf);
  score_kernel<<<R_ / 16, 256, 0, stream>>>(vbuf, pq, pidx, pwt);

  // gemm1: 32x16 = 512 blocks; gemm2: 32x8 = 256 blocks (1 per CU)
  gemm1_kernel<<<(R_ / 256) * (DFF / 256), 512, 0, stream>>>(
      xb, uwb, upb, pidx, pwt, gates, H);
  gemm2_kernel<<<(R_ / 256) * (DM / 128), 512, 0, stream>>>(
      H, dwb, dnb, out);
}

// Round 8
// 380.083 us; speedup vs baseline: 1.6592x; 1.6592x over previous
//
#include <hip/hip_runtime.h>
#include <hip/hip_bf16.h>
#include <math.h>

// Problem constants
#define R_   8192    // B*S rows
#define DM   1024    // d_model
#define DFF  4096    // d_ff
#define NP   64      // n_patterns
#define KN   8       // K neurons

typedef __bf16 bf16x8 __attribute__((ext_vector_type(8)));
typedef float  f32x4  __attribute__((ext_vector_type(4)));

__device__ __forceinline__ unsigned short f2bf(float f) {
  union { float f; unsigned u; } v; v.f = f;
  unsigned u = v.u;
  return (unsigned short)((u + 0x7FFFu + ((u >> 16) & 1u)) >> 16);
}

__device__ __forceinline__ float dot4(const float4 a, const float4 b) {
  return a.x * b.x + a.y * b.y + a.z * b.z + a.w * b.w;
}

__device__ __forceinline__ void fma4(float4& a, float w, const float4 s) {
  a.x += w * s.x; a.y += w * s.y; a.z += w * s.z; a.w += w * s.w;
}

// ---------------------------------------------------------------- f32 -> bf16
__global__ __launch_bounds__(256) void cvt_bf16_kernel(
    const float* __restrict__ in, unsigned short* __restrict__ out, int n8) {
  int i = blockIdx.x * 256 + threadIdx.x;
  if (i >= n8) return;
  const float4* p = (const float4*)in + (size_t)i * 2;
  float4 a = p[0], b = p[1];
  uint4 r;
  r.x = (unsigned)f2bf(a.x) | ((unsigned)f2bf(a.y) << 16);
  r.y = (unsigned)f2bf(a.z) | ((unsigned)f2bf(a.w) << 16);
  r.z = (unsigned)f2bf(b.x) | ((unsigned)f2bf(b.y) << 16);
  r.w = (unsigned)f2bf(b.z) | ((unsigned)f2bf(b.w) << 16);
  ((uint4*)out)[i] = r;
}

// -------------------------------------------------------------- v materialize
__global__ __launch_bounds__(256) void vcomp_kernel(
    const float* __restrict__ sn,    // [R_][8][1024]
    const float* __restrict__ tw,    // [R_][8]
    float* __restrict__ v)           // [R_][1024]
{
  const int r = blockIdx.x;
  const int t = threadIdx.x;
  float w[KN];
#pragma unroll
  for (int k = 0; k < KN; ++k) w[k] = tw[(size_t)r * KN + k];
  const float* base = sn + (size_t)r * (KN * DM) + t * 4;
  float4 a = {0.f, 0.f, 0.f, 0.f};
#pragma unroll
  for (int k = 0; k < KN; ++k) fma4(a, w[k], *(const float4*)(base + k * DM));
  *(float4*)(v + (size_t)r * DM + t * 4) = a;
}

// ------------------------------------------------- pattern scores/topk/softmax
__global__ __launch_bounds__(256, 2) void score_kernel(
    const float* __restrict__ v,     // [R_][1024]
    const float* __restrict__ pq,    // [64][1024]
    int*   __restrict__ out_idx,     // [R_][4]
    float* __restrict__ out_w)       // [R_][4]
{
  const int lane = threadIdx.x & 63;
  const int wave = threadIdx.x >> 6;
  const int pos0 = (blockIdx.x * 4 + wave) * 4;

  float4 vr[4][4];
#pragma unroll
  for (int p = 0; p < 4; ++p) {
    const float4* s = (const float4*)(v + (size_t)(pos0 + p) * DM + lane * 16);
    vr[p][0] = s[0]; vr[p][1] = s[1]; vr[p][2] = s[2]; vr[p][3] = s[3];
  }

  float sreg[4];
#pragma unroll 1
  for (int pat = 0; pat < NP; ++pat) {
    const float4* q = (const float4*)(pq + pat * DM + lane * 16);
    const float4 q0 = q[0], q1 = q[1], q2 = q[2], q3 = q[3];
    float part[4];
#pragma unroll
    for (int p = 0; p < 4; ++p)
      part[p] = dot4(q0, vr[p][0]) + dot4(q1, vr[p][1]) +
                dot4(q2, vr[p][2]) + dot4(q3, vr[p][3]);
#pragma unroll
    for (int off = 32; off >= 1; off >>= 1) {
#pragma unroll
      for (int p = 0; p < 4; ++p)
        part[p] += __shfl_xor(part[p], off, 64);
    }
    if (lane == pat) {
#pragma unroll
      for (int p = 0; p < 4; ++p) sreg[p] = part[p] * 0.03125f; // /sqrt(1024)
    }
  }

#pragma unroll
  for (int p = 0; p < 4; ++p) {
    float cur = sreg[p];
    float m0, m1, m2, m3; int i0, i1, i2, i3;
#define ARGMAX_STEP(MV, MI)                                   \
    {                                                         \
      float bv = cur; int bi = lane;                          \
      _Pragma("unroll")                                       \
      for (int off = 32; off >= 1; off >>= 1) {               \
        float ov = __shfl_xor(bv, off, 64);                   \
        int   oi = __shfl_xor(bi, off, 64);                   \
        if (ov > bv || (ov == bv && oi < bi)) { bv = ov; bi = oi; } \
      }                                                       \
      MV = bv; MI = bi;                                       \
      if (lane == bi) cur = -3.0e38f;                         \
    }
    ARGMAX_STEP(m0, i0) ARGMAX_STEP(m1, i1) ARGMAX_STEP(m2, i2) ARGMAX_STEP(m3, i3)
#undef ARGMAX_STEP
    const float e1 = __expf(m1 - m0), e2 = __expf(m2 - m0), e3 = __expf(m3 - m0);
    const float inv = 1.f / (1.f + e1 + e2 + e3);
    if (lane < 4) {
      const int r = pos0 + p;
      const int myi = (lane == 0) ? i0 : (lane == 1) ? i1 : (lane == 2) ? i2 : i3;
      const float mye = (lane == 0) ? 1.f : (lane == 1) ? e1 : (lane == 2) ? e2 : e3;
      out_idx[r * 4 + lane] = myi;
      out_w[r * 4 + lane] = mye * inv;
    }
  }
}

// ------------------------------------------------------------ GEMM machinery
__device__ __forceinline__ void gll16(const void* g, void* l) {
  __builtin_amdgcn_global_load_lds(
      (const __attribute__((address_space(1))) unsigned int*)g,
      (__attribute__((address_space(3))) unsigned int*)l, 16, 0, 0);
}

#define VMC(N) asm volatile("s_waitcnt vmcnt(%0)" ::"i"(N) : "memory")

// Pipelined NT GEMM, both shapes.  Tile 256x128, BK=64, 512 thr / 8 waves
// (4x2), wave-tile 64x64.  Ring-3 LDS buffers of 48KB (A 32KB + B 16KB).
// Per K-tile: 2 phases (ks0/ks1), 16 MFMA each.
//   ph0: 8x ds_read(ks0) ; stage tile t+2 -> buf[(t+2)%3]  (WAR-safe: that
//        buffer's last reads were tile t-1, drained via pre-MFMA lgkm(0)
//        and separated by >=1 barrier)
//        barrier ; lgkm(0) ; sched_barrier ; setprio(1) ; MFMA ; setprio(0) ; barrier
//   ph1: 8x ds_read(ks1) ; vmcnt(6)  <- confirms tile t+1's 6 loads, which
//        were issued at (t-1)ph0 = 3 phases (~500cy) earlier; never 0 until
//        the tail.  Then same sync + MFMA.
// LDS swizzle (verified 0-conflict, R4/R5): element (row, 16B-slot s of 8)
// stored at slot s ^ (row&7); writer pre-swizzles the global source slot
// (lane&7)^(lane>>3) (linear global_load_lds dest); reader slot
// (ks*4 + (lane>>4)) ^ (lane&7).
template <int K_, int NT, int NBN, int MODE>
__global__ __launch_bounds__(512) void gemm_kernel(
    const unsigned short* __restrict__ A,
    const unsigned short* __restrict__ Bm,
    const float* __restrict__ bias,
    const int*   __restrict__ pidx,
    const float* __restrict__ pwt,
    const float* __restrict__ gates,
    void* __restrict__ Cout)
{
  extern __shared__ char smem[];
  const int tid = threadIdx.x, lane = tid & 63, wid = tid >> 6;
  const int wr = wid >> 1, wc = wid & 1;

  // T1: bijective XCD chunking (grid % 8 == 0).  gemm1: chunks contiguous in
  // brow (A panel L2-resident); gemm2: contiguous in bcol (B panel resident).
  const int cpx = gridDim.x >> 3;
  const int swzb = ((int)blockIdx.x & 7) * cpx + ((int)blockIdx.x >> 3);
  int brow, bcol;
  if (MODE == 0) { brow = swzb / NBN; bcol = swzb % NBN; }
  else           { bcol = swzb >> 5;  brow = swzb & 31;  }

  const unsigned short* Ab = A  + (size_t)brow * 256 * K_;
  const unsigned short* Bb = Bm + (size_t)bcol * 128 * K_;

  // staging source offset (elements): row = h*64 + wid*8 + (lane>>3),
  // pre-swizzled slot (lane&7)^(lane>>3)
  const size_t aoff = (size_t)(wid * 8 + (lane >> 3)) * K_ +
                      ((lane & 7) ^ (lane >> 3)) * 8;
  // frag read bases (bytes within buffer region)
  const int sw0 = (((lane >> 4))     ^ (lane & 7)) * 16;
  const int sw1 = ((4 + (lane >> 4)) ^ (lane & 7)) * 16;
  const int aRdB = wr * 8192 + (lane & 15) * 128;
  const int bRdB = 32768 + wc * 8192 + (lane & 15) * 128;

  f32x4 acc[4][4];
#pragma unroll
  for (int m = 0; m < 4; ++m)
#pragma unroll
    for (int n = 0; n < 4; ++n) acc[m][n] = (f32x4){0.f, 0.f, 0.f, 0.f};

#define STG(OS, KT) {                                                         \
    _Pragma("unroll") for (int h_ = 0; h_ < 4; ++h_)                          \
      gll16(Ab + (KT) * 64 + (size_t)h_ * 64 * K_ + aoff,                     \
            smem + (OS) + h_ * 8192 + wid * 1024);                            \
    _Pragma("unroll") for (int h_ = 0; h_ < 2; ++h_)                          \
      gll16(Bb + (KT) * 64 + (size_t)h_ * 64 * K_ + aoff,                     \
            smem + (OS) + 32768 + h_ * 8192 + wid * 1024); }

#define RDS(OB, SW)                                                           \
    { const char* pa = smem + (OB) + aRdB;                                    \
      const char* pb = smem + (OB) + bRdB;                                    \
      _Pragma("unroll") for (int m_ = 0; m_ < 4; ++m_)                        \
        a[m_] = *(const bf16x8*)(pa + m_ * 2048 + (SW));                      \
      _Pragma("unroll") for (int n_ = 0; n_ < 4; ++n_)                        \
        b[n_] = *(const bf16x8*)(pb + n_ * 2048 + (SW)); }

#define MIDSYNC                                                               \
    __builtin_amdgcn_s_barrier();                                             \
    asm volatile("s_waitcnt lgkmcnt(0)" ::: "memory");                        \
    __builtin_amdgcn_sched_barrier(0);

#define MF16                                                                  \
    __builtin_amdgcn_s_setprio(1);                                            \
    _Pragma("unroll") for (int m_ = 0; m_ < 4; ++m_)                          \
    _Pragma("unroll") for (int n_ = 0; n_ < 4; ++n_)                          \
      acc[m_][n_] = __builtin_amdgcn_mfma_f32_16x16x32_bf16(                  \
          a[m_], b[n_], acc[m_][n_], 0, 0, 0);                                \
    __builtin_amdgcn_s_setprio(0);                                            \
    __builtin_amdgcn_s_barrier();

  // prologue: stage tiles 0,1; confirm tile 0 (tile 1's 6 stay in flight)
  STG(0, 0)
  STG(49152, 1)
  VMC(6);
  __builtin_amdgcn_s_barrier();

  int o0 = 0, o1 = 49152, o2 = 98304;
#pragma unroll 1
  for (int t = 0; t < NT; ++t) {
    bf16x8 a[4], b[4];
    // ---- ph0 (ks0)
    RDS(o0, sw0)
    if (t + 2 < NT) STG(o2, t + 2)
    MIDSYNC
    MF16
    // ---- ph1 (ks1)
    RDS(o0, sw1)
    if (t < NT - 2) { VMC(6); } else { VMC(0); }
    MIDSYNC
    MF16
    const int tmp = o0; o0 = o1; o1 = o2; o2 = tmp;
  }
#undef STG
#undef RDS
#undef MIDSYNC
#undef MF16

  // ---- epilogue. C/D layout: col = lane&15, row = (lane>>4)*4 + j.
  const int crow0 = brow * 256 + wr * 64;
  const int ccol0 = bcol * 128 + wc * 64 + (lane & 15);
  const int rsub  = (lane >> 4) * 4;

  if (MODE == 0) {
    unsigned short* H = (unsigned short*)Cout;
#pragma unroll
    for (int m = 0; m < 4; ++m) {
      const int rbase = crow0 + m * 16 + rsub;
      int   ia[4][4];
      float wa[4][4];
#pragma unroll
      for (int j = 0; j < 4; ++j) {
        const int4   iq = *(const int4*)(pidx + (size_t)(rbase + j) * 4);
        const float4 wq = *(const float4*)(pwt + (size_t)(rbase + j) * 4);
        ia[j][0] = iq.x; ia[j][1] = iq.y; ia[j][2] = iq.z; ia[j][3] = iq.w;
        wa[j][0] = wq.x; wa[j][1] = wq.y; wa[j][2] = wq.z; wa[j][3] = wq.w;
      }
#pragma unroll
      for (int n = 0; n < 4; ++n) {
        const int col = ccol0 + n * 16;
        const float ub = bias[col];
#pragma unroll
        for (int j = 0; j < 4; ++j) {
          float g = wa[j][0] * gates[(size_t)ia[j][0] * DFF + col]
                  + wa[j][1] * gates[(size_t)ia[j][1] * DFF + col]
                  + wa[j][2] * gates[(size_t)ia[j][2] * DFF + col]
                  + wa[j][3] * gates[(size_t)ia[j][3] * DFF + col];
          const float u   = acc[m][n][j] + ub;
          const float val = u * (1.f / (1.f + __expf(-g)));
          const float h   = 0.5f * val * (1.f + erff(val * 0.70710678118654752f));
          H[(size_t)(rbase + j) * DFF + col] = f2bf(h);
        }
      }
    }
  } else {
    float* O = (float*)Cout;
#pragma unroll
    for (int m = 0; m < 4; ++m) {
      const int rbase = crow0 + m * 16 + rsub;
#pragma unroll
      for (int n = 0; n < 4; ++n) {
        const int col = ccol0 + n * 16;
        const float db = bias[col];
#pragma unroll
        for (int j = 0; j < 4; ++j)
          O[(size_t)(rbase + j) * DM + col] = acc[m][n][j] + db;
      }
    }
  }
}

// ---------------------------------------------------------------------- launch
extern "C" void kernel_launch(void* const* d_in, const int* in_sizes, int n_in,
                              void* d_out, int out_size, void* d_ws, size_t ws_size,
                              hipStream_t stream) {
  const float* x     = (const float*)d_in[0];
  const float* tw    = (const float*)d_in[3];
  const float* sn    = (const float*)d_in[4];
  const float* pq    = (const float*)d_in[5];
  const float* gates = (const float*)d_in[6];
  const float* upw   = (const float*)d_in[7];
  const float* upb   = (const float*)d_in[8];
  const float* dnw   = (const float*)d_in[9];
  const float* dnb   = (const float*)d_in[10];
  float* out = (float*)d_out;

  char* p = (char*)d_ws;
  unsigned short* xb  = (unsigned short*)p; p += (size_t)R_ * DM * 2;
  unsigned short* uwb = (unsigned short*)p; p += (size_t)DFF * DM * 2;
  unsigned short* dwb = (unsigned short*)p; p += (size_t)DM * DFF * 2;
  unsigned short* H   = (unsigned short*)p; p += (size_t)R_ * DFF * 2;
  int*   pidx = (int*)p;   p += (size_t)R_ * 4 * sizeof(int);
  float* pwt  = (float*)p; p += (size_t)R_ * 4 * sizeof(float);
  float* vbuf = (float*)p; p += (size_t)R_ * DM * sizeof(float);

  cvt_bf16_kernel<<<(R_ * DM / 8) / 256, 256, 0, stream>>>(x, xb, R_ * DM / 8);
  cvt_bf16_kernel<<<(DFF * DM / 8) / 256, 256, 0, stream>>>(upw, uwb, DFF * DM / 8);
  cvt_bf16_kernel<<<(DM * DFF / 8) / 256, 256, 0, stream>>>(dnw, dwb, DM * DFF / 8);

  vcomp_kernel<<<R_, 256, 0, stream>>>(sn, tw, vbuf);
  score_kernel<<<R_ / 16, 256, 0, stream>>>(vbuf, pq, pidx, pwt);

  // gemm1: K=1024, NT=16, grid 32x32=1024; gemm2: K=4096, NT=64, grid 32x8=256
  auto* k1 = gemm_kernel<DM, 16, 32, 0>;
  auto* k2 = gemm_kernel<DFF, 64, 8, 1>;
  hipFuncSetAttribute((const void*)k1,
                      hipFuncAttributeMaxDynamicSharedMemorySize, 147456);
  hipFuncSetAttribute((const void*)k2,
                      hipFuncAttributeMaxDynamicSharedMemorySize, 147456);

  k1<<<(R_ / 256) * (DFF / 128), 512, 147456, stream>>>(
      xb, uwb, upb, pidx, pwt, gates, (void*)H);
  k2<<<(R_ / 256) * (DM / 128), 512, 147456, stream>>>(
      H, dwb, dnb, nullptr, nullptr, nullptr, (void*)out);
}